// Round 4
// baseline (1626.445 us; speedup 1.0000x reference)
//
#include <hip/hip_runtime.h>
#include <math.h>

#define DIM    512
#define KCB    8192
#define NROWS  32768

typedef _Float16 f16x8 __attribute__((ext_vector_type(8)));
typedef float    f32x4 __attribute__((ext_vector_type(4)));

// ---- workspace layout (main path) ----
#define OFF_ZH    0ull                    // f16 Z  [32768][512] = 33554432 B
#define OFF_EH    33554432ull             // f16 E  [8192][512]  =  8388608 B
#define OFF_EE    41943040ull             // f32 ee [8192]
#define OFF_ZZ    41975808ull             // f32 zz [32768]
#define OFF_CNT   42106880ull             // u32 cnt[32768]
#define OFF_CAND  42237952ull             // u32 cand[32768][64]
#define OFF_IDX   50626560ull             // i32 idx[32768]
#define OFF_LOSS  50757632ull             // f64 loss accumulator
#define WS_NEEDED 50757640ull
#define CAP 64
#define MARGIN 5.0e-4f

// direct-to-LDS 16B DMA (dest = wave-uniform base + lane*16; swizzle goes on
// the per-lane GLOBAL source address)
__device__ __forceinline__ void gl_lds16(const void* g, void* l) {
    __builtin_amdgcn_global_load_lds(
        (const __attribute__((address_space(1))) unsigned int*)g,
        (__attribute__((address_space(3))) unsigned int*)l, 16, 0, 0);
}

// ---------------------------------------------------------------------------
// numpy-pairwise sum of squares, 512 floats (numerics-critical, unchanged).
// ---------------------------------------------------------------------------
__device__ __forceinline__ float pairwise512_sq_v(const float* __restrict__ p) {
    float blk[4];
#pragma unroll
    for (int b = 0; b < 4; ++b) {
        const float4* a4 = (const float4*)(p + b * 128);
        float4 v0 = a4[0], v1 = a4[1];
        float r[8];
        r[0] = __fmul_rn(v0.x, v0.x); r[1] = __fmul_rn(v0.y, v0.y);
        r[2] = __fmul_rn(v0.z, v0.z); r[3] = __fmul_rn(v0.w, v0.w);
        r[4] = __fmul_rn(v1.x, v1.x); r[5] = __fmul_rn(v1.y, v1.y);
        r[6] = __fmul_rn(v1.z, v1.z); r[7] = __fmul_rn(v1.w, v1.w);
#pragma unroll
        for (int i = 1; i < 16; ++i) {
            v0 = a4[i * 2]; v1 = a4[i * 2 + 1];
            r[0] = __fadd_rn(r[0], __fmul_rn(v0.x, v0.x));
            r[1] = __fadd_rn(r[1], __fmul_rn(v0.y, v0.y));
            r[2] = __fadd_rn(r[2], __fmul_rn(v0.z, v0.z));
            r[3] = __fadd_rn(r[3], __fmul_rn(v0.w, v0.w));
            r[4] = __fadd_rn(r[4], __fmul_rn(v1.x, v1.x));
            r[5] = __fadd_rn(r[5], __fmul_rn(v1.y, v1.y));
            r[6] = __fadd_rn(r[6], __fmul_rn(v1.z, v1.z));
            r[7] = __fadd_rn(r[7], __fmul_rn(v1.w, v1.w));
        }
        blk[b] = __fadd_rn(__fadd_rn(__fadd_rn(r[0], r[1]), __fadd_rn(r[2], r[3])),
                           __fadd_rn(__fadd_rn(r[4], r[5]), __fadd_rn(r[6], r[7])));
    }
    return __fadd_rn(__fadd_rn(blk[0], blk[1]), __fadd_rn(blk[2], blk[3]));
}

__global__ void ee_kernel(const float* __restrict__ E, float* __restrict__ ee) {
    int k = blockIdx.x * blockDim.x + threadIdx.x;
    if (k < KCB) ee[k] = pairwise512_sq_v(E + (size_t)k * DIM);
}

__global__ void zz_kernel(const float* __restrict__ Z, float* __restrict__ zz) {
    int r = blockIdx.x * blockDim.x + threadIdx.x;
    if (r < NROWS) zz[r] = pairwise512_sq_v(Z + (size_t)r * DIM);
}

__global__ void cvt_kernel(const float* __restrict__ in, _Float16* __restrict__ out, int n8) {
    int i = blockIdx.x * blockDim.x + threadIdx.x;
    if (i >= n8) return;
    const float4* p = (const float4*)in + (size_t)i * 2;
    float4 v0 = p[0], v1 = p[1];
    f16x8 h;
    h[0] = (_Float16)v0.x; h[1] = (_Float16)v0.y; h[2] = (_Float16)v0.z; h[3] = (_Float16)v0.w;
    h[4] = (_Float16)v1.x; h[5] = (_Float16)v1.y; h[6] = (_Float16)v1.z; h[7] = (_Float16)v1.w;
    *(f16x8*)(out + (size_t)i * 8) = h;
}

// ---------------------------------------------------------------------------
// Screen v2: 512 blocks x 256 threads (4 waves). Block = 64 rows, sweeps 32
// tiles of 256 cols. A-panel [64][512] f16 resident (64 KiB, XOR-swizzled
// 16B slots, staged once via global_load_lds). B double-buffered
// 2 x [256][64] f16 (2 x 32 KiB), restaged per kstep via global_load_lds with
// pre-swizzled global source. 2-phase schedule: counted vmcnt(8) + raw
// s_barrier (never vmcnt(0) mid-loop); lgkmcnt(0) before the re-stage barrier.
// Wave w owns cols [w*64, w*64+64): 4x4 16x16x32 f16 frags, K accumulated
// over 8 ksteps. Epilogue per tile: crit = ee - 2*dot, wave-local running
// min, append candidates within MARGIN.
// ---------------------------------------------------------------------------
__global__ __launch_bounds__(256, 1)
void screen_kernel(const _Float16* __restrict__ Zh, const _Float16* __restrict__ Eh,
                   const float* __restrict__ ee,
                   unsigned int* __restrict__ cnt, unsigned int* __restrict__ cand) {
    __shared__ __align__(16) char lds[64 * 1024 + 2 * 32 * 1024];  // 128 KiB
    char* Ab = lds;                   // [64 rows][64 slots * 16B]
    char* Bb = lds + 65536;           // 2 x [256 cols][8 slots * 16B]

    const int tid = threadIdx.x;
    const int l = tid & 63;
    const int w = tid >> 6;           // wave 0..3
    const int rowBase = blockIdx.x * 64;

    // ---- stage A panel once (16 DMA per wave; dest linear in lane)
#pragma unroll
    for (int i = 0; i < 16; ++i) {
        const int r = w + i * 4;                       // wave-uniform
        gl_lds16(Zh + (size_t)(rowBase + r) * DIM + (l ^ (r & 7)) * 8,
                 Ab + r * 1024 + l * 16);
    }

#define STAGE_B(buf, step) do {                                                \
        const int _tile = (step) >> 3, _ks = (step) & 7;                       \
        _Pragma("unroll")                                                      \
        for (int _i = 0; _i < 8; ++_i) {                                       \
            const int _c = w * 8 + (l >> 3) + _i * 32;                         \
            gl_lds16(Eh + (size_t)(_tile * 256 + _c) * DIM + _ks * 64          \
                         + ((l & 7) ^ (_c & 7)) * 8,                           \
                     Bb + (buf) * 32768 + w * 1024 + _i * 4096 + l * 16);      \
        }                                                                      \
    } while (0)

    STAGE_B(0, 0);
    STAGE_B(1, 1);

    float runmin[16];
#pragma unroll
    for (int q = 0; q < 16; ++q) runmin[q] = __builtin_inff();

    f32x4 acc[4][4];

    for (int step = 0; step < 256; ++step) {
        const int ks = step & 7;
        const int buf = step & 1;
        if (ks == 0) {
#pragma unroll
            for (int m = 0; m < 4; ++m)
#pragma unroll
                for (int n = 0; n < 4; ++n) acc[m][n] = (f32x4){0.f, 0.f, 0.f, 0.f};
        }
        // wait: oldest 8 DMAs (this step's B, plus A on step 0) complete
        if (step == 255) asm volatile("s_waitcnt vmcnt(0)" ::: "memory");
        else             asm volatile("s_waitcnt vmcnt(8)" ::: "memory");
        asm volatile("s_barrier" ::: "memory");

        const char* B0 = Bb + buf * 32768;
#pragma unroll
        for (int k2 = 0; k2 < 2; ++k2) {
            f16x8 af[4], bf[4];
            const int s = ks * 8 + k2 * 4 + (l >> 4);
#pragma unroll
            for (int m = 0; m < 4; ++m) {
                const int r = m * 16 + (l & 15);
                af[m] = *(const f16x8*)(Ab + r * 1024 + (s ^ (r & 7)) * 16);
            }
            const int sb = k2 * 4 + (l >> 4);
#pragma unroll
            for (int n = 0; n < 4; ++n) {
                const int c = w * 64 + n * 16 + (l & 15);
                bf[n] = *(const f16x8*)(B0 + c * 128 + (sb ^ (c & 7)) * 16);
            }
#pragma unroll
            for (int m = 0; m < 4; ++m)
#pragma unroll
                for (int n = 0; n < 4; ++n)
                    acc[m][n] = __builtin_amdgcn_mfma_f32_16x16x32_f16(af[m], bf[n], acc[m][n], 0, 0, 0);
        }

        if (ks == 7) {
            const int tile = step >> 3;
            float eev[4];
#pragma unroll
            for (int n = 0; n < 4; ++n)
                eev[n] = ee[tile * 256 + w * 64 + n * 16 + (l & 15)];
#pragma unroll
            for (int m = 0; m < 4; ++m) {
#pragma unroll
                for (int r = 0; r < 4; ++r) {
                    float cr[4];
#pragma unroll
                    for (int n = 0; n < 4; ++n) cr[n] = fmaf(-2.0f, acc[m][n][r], eev[n]);
                    float mn = fminf(fminf(cr[0], cr[1]), fminf(cr[2], cr[3]));
#pragma unroll
                    for (int off = 1; off < 16; off <<= 1)
                        mn = fminf(mn, __shfl_xor(mn, off, 64));
                    const int q = m * 4 + r;
                    float rm = fminf(runmin[q], mn);
                    runmin[q] = rm;
                    const float thr = rm + MARGIN;
                    const int rowg = rowBase + m * 16 + (l >> 4) * 4 + r;
#pragma unroll
                    for (int n = 0; n < 4; ++n) {
                        if (cr[n] <= thr) {
                            unsigned pos = atomicAdd(&cnt[rowg], 1u);
                            if (pos < CAP)
                                cand[(size_t)rowg * CAP + pos] =
                                    (unsigned)(tile * 256 + w * 64 + n * 16 + (l & 15));
                        }
                    }
                }
            }
        }

        // all my ds_reads landed in regs before anyone overwrites this buffer
        asm volatile("s_waitcnt lgkmcnt(0)" ::: "memory");
        asm volatile("s_barrier" ::: "memory");
        if (step + 2 < 256) STAGE_B(buf, step + 2);
    }
#undef STAGE_B
}

// ---------------------------------------------------------------------------
// Exact rescore: one wave per row, one candidate per lane; float4 loads,
// sequential fmaf chain in ascending k (bit-identical to the passing chain).
// c==1 -> winner is the sole candidate, skip the dot entirely.
// ---------------------------------------------------------------------------
__global__ void rescore_kernel(const float* __restrict__ Z, const float* __restrict__ E,
                               const float* __restrict__ zz, const float* __restrict__ ee,
                               const unsigned int* __restrict__ cnt,
                               const unsigned int* __restrict__ cand,
                               int* __restrict__ idx) {
    int row = blockIdx.x;
    int l = threadIdx.x;  // 64
    unsigned c = cnt[row]; if (c > CAP) c = CAP;
    if (c == 1) {
        if (l == 0) idx[row] = (int)cand[(size_t)row * CAP];
        return;
    }
    float d2 = __builtin_inff();
    int kk = 0x7FFFFFFF;
    if (l < (int)c) {
        int k = (int)cand[(size_t)row * CAP + l];
        const float4* zr4 = (const float4*)(Z + (size_t)row * DIM);
        const float4* er4 = (const float4*)(E + (size_t)k * DIM);
        float s = 0.0f;
#pragma unroll 8
        for (int i = 0; i < DIM / 4; ++i) {
            float4 z4 = zr4[i], e4 = er4[i];
            s = __builtin_fmaf(z4.x, e4.x, s);
            s = __builtin_fmaf(z4.y, e4.y, s);
            s = __builtin_fmaf(z4.z, e4.z, s);
            s = __builtin_fmaf(z4.w, e4.w, s);
        }
        float t = __builtin_fmaf(-2.0f, s, zz[row]);
        d2 = __fadd_rn(t, ee[k]);
        kk = k;
    }
#pragma unroll
    for (int off = 32; off > 0; off >>= 1) {
        float od = __shfl_down(d2, off, 64);
        int ok = __shfl_down(kk, off, 64);
        if (od < d2 || (od == d2 && ok < kk)) { d2 = od; kk = ok; }
    }
    if (l == 0) idx[row] = kk;
}

// ---------------------------------------------------------------------------
// Gather + straight-through output + f64 loss (unchanged, proven).
// ---------------------------------------------------------------------------
__global__ void gather_kernel(const float* __restrict__ Z, const float* __restrict__ E,
                              const int* __restrict__ idx, float* __restrict__ outZ,
                              float* __restrict__ outIdxF, double* __restrict__ lossAcc) {
    int row = blockIdx.x;
    int t = threadIdx.x;  // 64
    int k = idx[row];
    const float* zr = Z + (size_t)row * DIM;
    const float* er = E + (size_t)k * DIM;
    float* orow = outZ + (size_t)row * DIM;
    double s = 0.0;
#pragma unroll
    for (int i = 0; i < 2; ++i) {
        int off = (t + i * 64) * 4;
        float4 z4 = *(const float4*)(zr + off);
        float4 e4 = *(const float4*)(er + off);
        float dx = __fsub_rn(e4.x, z4.x);
        float dy = __fsub_rn(e4.y, z4.y);
        float dz = __fsub_rn(e4.z, z4.z);
        float dw = __fsub_rn(e4.w, z4.w);
        float4 st;
        st.x = __fadd_rn(z4.x, dx);
        st.y = __fadd_rn(z4.y, dy);
        st.z = __fadd_rn(z4.z, dz);
        st.w = __fadd_rn(z4.w, dw);
        *(float4*)(orow + off) = st;
        s += (double)dx * dx + (double)dy * dy + (double)dz * dz + (double)dw * dw;
    }
#pragma unroll
    for (int o = 32; o > 0; o >>= 1) s += __shfl_down(s, o, 64);
    if (t == 0) {
        atomicAdd(lossAcc, s);
        outIdxF[row] = (float)k;
    }
}

__global__ void finalize_kernel(const double* __restrict__ lossAcc,
                                float* __restrict__ outLoss) {
    double m = *lossAcc / (double)((size_t)NROWS * DIM);
    float mf = (float)m;
    float c = __fmul_rn(0.25f, mf);
    *outLoss = __fadd_rn(c, mf);
}

// ---------------------------------------------------------------------------
// Fallback (ws too small): round-1 proven-correct VALU argmin, verbatim.
// ---------------------------------------------------------------------------
__device__ __forceinline__ float pairwise512_sq(const float* __restrict__ p) {
    float blk[4];
#pragma unroll
    for (int b = 0; b < 4; ++b) {
        const float* a = p + b * 128;
        float r[8];
#pragma unroll
        for (int j = 0; j < 8; ++j) r[j] = __fmul_rn(a[j], a[j]);
#pragma unroll
        for (int i = 8; i < 128; i += 8) {
#pragma unroll
            for (int j = 0; j < 8; ++j)
                r[j] = __fadd_rn(r[j], __fmul_rn(a[i + j], a[i + j]));
        }
        blk[b] = __fadd_rn(__fadd_rn(__fadd_rn(r[0], r[1]), __fadd_rn(r[2], r[3])),
                           __fadd_rn(__fadd_rn(r[4], r[5]), __fadd_rn(r[6], r[7])));
    }
    return __fadd_rn(__fadd_rn(blk[0], blk[1]), __fadd_rn(blk[2], blk[3]));
}

__global__ __launch_bounds__(512, 2)
void argmin_fallback(const float* __restrict__ Z, const float* __restrict__ E,
                     const float* __restrict__ ee, int* __restrict__ outIdx) {
    __shared__ __align__(16) char smem[(32 * 132 + 32 * 260) * 4];
    float (*As)[132] = (float (*)[132])smem;
    float (*Bs)[260] = (float (*)[260])(smem + 32 * 132 * 4);
    __shared__ float zzs[128];
    const int tid = threadIdx.x;
    const int tx = tid & 31;
    const int ty = tid >> 5;
    const int rowBase = blockIdx.x * 128;
    if (tid < 128) zzs[tid] = pairwise512_sq(Z + (size_t)(rowBase + tid) * DIM);
    __syncthreads();
    float zz[8];
#pragma unroll
    for (int m = 0; m < 8; ++m) zz[m] = zzs[ty * 8 + m];
    float bestV[8]; int bestI[8];
#pragma unroll
    for (int m = 0; m < 8; ++m) { bestV[m] = __builtin_inff(); bestI[m] = 0; }
    for (int tile = 0; tile < 32; ++tile) {
        float acc[8][8];
#pragma unroll
        for (int m = 0; m < 8; ++m)
#pragma unroll
            for (int n = 0; n < 8; ++n) acc[m][n] = 0.0f;
        for (int kc = 0; kc < DIM; kc += 32) {
            __syncthreads();
#pragma unroll
            for (int i = 0; i < 2; ++i) {
                int id4 = tid + i * 512;
                int r = id4 >> 3, c = id4 & 7;
                float4 v = *(const float4*)(Z + (size_t)(rowBase + r) * DIM + kc + c * 4);
                As[c * 4 + 0][r] = v.x; As[c * 4 + 1][r] = v.y;
                As[c * 4 + 2][r] = v.z; As[c * 4 + 3][r] = v.w;
            }
#pragma unroll
            for (int i = 0; i < 4; ++i) {
                int id4 = tid + i * 512;
                int r = id4 >> 3, c = id4 & 7;
                float4 v = *(const float4*)(E + (size_t)(tile * 256 + r) * DIM + kc + c * 4);
                Bs[c * 4 + 0][r] = v.x; Bs[c * 4 + 1][r] = v.y;
                Bs[c * 4 + 2][r] = v.z; Bs[c * 4 + 3][r] = v.w;
            }
            __syncthreads();
#pragma unroll
            for (int kk = 0; kk < 32; ++kk) {
                float a[8], b[8];
                *(float4*)&a[0] = *(const float4*)&As[kk][ty * 8];
                *(float4*)&a[4] = *(const float4*)&As[kk][ty * 8 + 4];
                *(float4*)&b[0] = *(const float4*)&Bs[kk][tx * 8];
                *(float4*)&b[4] = *(const float4*)&Bs[kk][tx * 8 + 4];
#pragma unroll
                for (int m = 0; m < 8; ++m)
#pragma unroll
                    for (int n = 0; n < 8; ++n)
                        acc[m][n] = __builtin_fmaf(a[m], b[n], acc[m][n]);
            }
        }
#pragma unroll
        for (int m = 0; m < 8; ++m) {
#pragma unroll
            for (int n = 0; n < 8; ++n) {
                float t = __builtin_fmaf(-2.0f, acc[m][n], zz[m]);
                float d2 = __fadd_rn(t, ee[tile * 256 + tx * 8 + n]);
                int kidx = tile * 256 + tx * 8 + n;
                if (d2 < bestV[m]) { bestV[m] = d2; bestI[m] = kidx; }
            }
        }
    }
    __syncthreads();
    float (*redV)[33] = (float (*)[33])smem;
    int   (*redI)[33] = (int (*)[33])(smem + 128 * 33 * 4);
#pragma unroll
    for (int m = 0; m < 8; ++m) {
        redV[ty * 8 + m][tx] = bestV[m];
        redI[ty * 8 + m][tx] = bestI[m];
    }
    __syncthreads();
    if (tid < 128) {
        float bv = redV[tid][0]; int bi = redI[tid][0];
        for (int j = 1; j < 32; ++j) {
            float v = redV[tid][j]; int ii = redI[tid][j];
            if (v < bv || (v == bv && ii < bi)) { bv = v; bi = ii; }
        }
        outIdx[rowBase + tid] = bi;
    }
}

// ---------------------------------------------------------------------------
extern "C" void kernel_launch(void* const* d_in, const int* in_sizes, int n_in,
                              void* d_out, int out_size, void* d_ws, size_t ws_size,
                              hipStream_t stream) {
    const float* Z = (const float*)d_in[0];
    const float* E = (const float*)d_in[1];
    float* out = (float*)d_out;
    float* zq_out = out;
    float* loss_out = out + (size_t)NROWS * DIM;
    float* idxf_out = loss_out + 1;

    if (ws_size >= WS_NEEDED) {
        _Float16* Zh = (_Float16*)((char*)d_ws + OFF_ZH);
        _Float16* Eh = (_Float16*)((char*)d_ws + OFF_EH);
        float* ee = (float*)((char*)d_ws + OFF_EE);
        float* zz = (float*)((char*)d_ws + OFF_ZZ);
        unsigned int* cnt = (unsigned int*)((char*)d_ws + OFF_CNT);
        unsigned int* cand = (unsigned int*)((char*)d_ws + OFF_CAND);
        int* idx = (int*)((char*)d_ws + OFF_IDX);
        double* lossAcc = (double*)((char*)d_ws + OFF_LOSS);

        hipMemsetAsync(cnt, 0, NROWS * sizeof(unsigned int), stream);
        hipMemsetAsync(lossAcc, 0, sizeof(double), stream);
        cvt_kernel<<<(NROWS * DIM / 8 + 255) / 256, 256, 0, stream>>>(Z, Zh, NROWS * DIM / 8);
        cvt_kernel<<<(KCB * DIM / 8 + 255) / 256, 256, 0, stream>>>(E, Eh, KCB * DIM / 8);
        ee_kernel<<<KCB / 256, 256, 0, stream>>>(E, ee);
        zz_kernel<<<NROWS / 256, 256, 0, stream>>>(Z, zz);
        screen_kernel<<<NROWS / 64, 256, 0, stream>>>(Zh, Eh, ee, cnt, cand);
        rescore_kernel<<<NROWS, 64, 0, stream>>>(Z, E, zz, ee, cnt, cand, idx);
        gather_kernel<<<NROWS, 64, 0, stream>>>(Z, E, idx, zq_out, idxf_out, lossAcc);
        finalize_kernel<<<1, 1, 0, stream>>>(lossAcc, loss_out);
    } else {
        float* ee = (float*)d_ws;
        int* idx = (int*)((char*)d_ws + 32768);
        double* lossAcc = (double*)((char*)d_ws + 163840);
        hipMemsetAsync(lossAcc, 0, sizeof(double), stream);
        ee_kernel<<<KCB / 256, 256, 0, stream>>>(E, ee);
        argmin_fallback<<<NROWS / 128, 512, 0, stream>>>(Z, E, ee, idx);
        gather_kernel<<<NROWS, 64, 0, stream>>>(Z, E, idx, zq_out, idxf_out, lossAcc);
        finalize_kernel<<<1, 1, 0, stream>>>(lossAcc, loss_out);
    }
}

// Round 5
// 1008.815 us; speedup vs baseline: 1.6122x; 1.6122x over previous
//
#include <hip/hip_runtime.h>
#include <math.h>

#define DIM    512
#define KCB    8192
#define NROWS  32768

typedef _Float16 f16x8 __attribute__((ext_vector_type(8)));
typedef float    f32x4 __attribute__((ext_vector_type(4)));

// ---- workspace layout (main path) ----
#define OFF_ZH    0ull                    // f16 Z  [32768][512] = 33554432 B
#define OFF_EH    33554432ull             // f16 E*8192 [8192][512] = 8388608 B
#define OFF_EE    41943040ull             // f32 ee [8192]
#define OFF_ZZ    41975808ull             // f32 zz [32768]
#define OFF_CNT   42106880ull             // u32 cnt[32768]
#define OFF_CAND  42237952ull             // u32 cand[32768][64]
#define OFF_IDX   50626560ull             // i32 idx[32768] (fallback only)
#define OFF_LOSS  50757632ull             // f64 loss accumulator
#define WS_NEEDED 50757640ull
#define CAP 64
// screen keeps k if dot16_scaled >= runmax - THR. Scale = 2^13 on E.
// Equivalent dot-margin 2.5e-4 (r3-proven); required slack ~1.2e-4.
#define THR 2.048f

// direct-to-LDS 16B DMA (dest = wave-uniform base + lane*16; swizzle goes on
// the per-lane GLOBAL source address)
__device__ __forceinline__ void gl_lds16(const void* g, void* l) {
    __builtin_amdgcn_global_load_lds(
        (const __attribute__((address_space(1))) unsigned int*)g,
        (__attribute__((address_space(3))) unsigned int*)l, 16, 0, 0);
}

// ---------------------------------------------------------------------------
// numpy-pairwise sum of squares, 512 floats (numerics-critical, unchanged).
// ---------------------------------------------------------------------------
__device__ __forceinline__ float pairwise512_sq_v(const float* __restrict__ p) {
    float blk[4];
#pragma unroll
    for (int b = 0; b < 4; ++b) {
        const float4* a4 = (const float4*)(p + b * 128);
        float4 v0 = a4[0], v1 = a4[1];
        float r[8];
        r[0] = __fmul_rn(v0.x, v0.x); r[1] = __fmul_rn(v0.y, v0.y);
        r[2] = __fmul_rn(v0.z, v0.z); r[3] = __fmul_rn(v0.w, v0.w);
        r[4] = __fmul_rn(v1.x, v1.x); r[5] = __fmul_rn(v1.y, v1.y);
        r[6] = __fmul_rn(v1.z, v1.z); r[7] = __fmul_rn(v1.w, v1.w);
#pragma unroll
        for (int i = 1; i < 16; ++i) {
            v0 = a4[i * 2]; v1 = a4[i * 2 + 1];
            r[0] = __fadd_rn(r[0], __fmul_rn(v0.x, v0.x));
            r[1] = __fadd_rn(r[1], __fmul_rn(v0.y, v0.y));
            r[2] = __fadd_rn(r[2], __fmul_rn(v0.z, v0.z));
            r[3] = __fadd_rn(r[3], __fmul_rn(v0.w, v0.w));
            r[4] = __fadd_rn(r[4], __fmul_rn(v1.x, v1.x));
            r[5] = __fadd_rn(r[5], __fmul_rn(v1.y, v1.y));
            r[6] = __fadd_rn(r[6], __fmul_rn(v1.z, v1.z));
            r[7] = __fadd_rn(r[7], __fmul_rn(v1.w, v1.w));
        }
        blk[b] = __fadd_rn(__fadd_rn(__fadd_rn(r[0], r[1]), __fadd_rn(r[2], r[3])),
                           __fadd_rn(__fadd_rn(r[4], r[5]), __fadd_rn(r[6], r[7])));
    }
    return __fadd_rn(__fadd_rn(blk[0], blk[1]), __fadd_rn(blk[2], blk[3]));
}

__global__ void ee_kernel(const float* __restrict__ E, float* __restrict__ ee) {
    int k = blockIdx.x * blockDim.x + threadIdx.x;
    if (k < KCB) ee[k] = pairwise512_sq_v(E + (size_t)k * DIM);
}

__global__ void zz_kernel(const float* __restrict__ Z, float* __restrict__ zz) {
    int r = blockIdx.x * blockDim.x + threadIdx.x;
    if (r < NROWS) zz[r] = pairwise512_sq_v(Z + (size_t)r * DIM);
}

// f32 -> f16 (RNE) with optional exact power-of-2 prescale
__global__ void cvt_kernel(const float* __restrict__ in, _Float16* __restrict__ out,
                           int n8, float scale) {
    int i = blockIdx.x * blockDim.x + threadIdx.x;
    if (i >= n8) return;
    const float4* p = (const float4*)in + (size_t)i * 2;
    float4 v0 = p[0], v1 = p[1];
    f16x8 h;
    h[0] = (_Float16)(v0.x * scale); h[1] = (_Float16)(v0.y * scale);
    h[2] = (_Float16)(v0.z * scale); h[3] = (_Float16)(v0.w * scale);
    h[4] = (_Float16)(v1.x * scale); h[5] = (_Float16)(v1.y * scale);
    h[6] = (_Float16)(v1.z * scale); h[7] = (_Float16)(v1.w * scale);
    *(f16x8*)(out + (size_t)i * 8) = h;
}

// ---------------------------------------------------------------------------
// Screen v3: 256 blocks x 512 thr (8 waves: wrow=w>>2 in {0,1}, wcol=w&3).
// A-panel [128 rows][512 K] f16 resident in LDS (128 KiB, XOR-swizzled 16B
// units, DMA-staged once). B dbuf 2 x [256 cols][32 K] f16 (2 x 16 KiB),
// restaged per kstep via 2 DMAs/wave with swizzle on the global source.
// Per kstep per wave: 4 A-frag + 4 B-frag ds_read_b128, 16 mfma 16x16x32.
// Counted vmcnt(2) (one B batch stays in flight), raw s_barrier, setprio
// around the MFMA cluster. Epilogue per tile: pure-register dot-max + rare
// candidate appends (global atomicAdd only on hit lanes).
// ---------------------------------------------------------------------------
__global__ __launch_bounds__(512, 2)
void screen_kernel(const _Float16* __restrict__ Zh, const _Float16* __restrict__ Eh,
                   unsigned int* __restrict__ cnt, unsigned int* __restrict__ cand) {
    __shared__ __align__(16) char lds[128 * 1024 + 2 * 16384];  // 160 KiB exactly
    char* Ab = lds;                   // [128 rows][64 units of 16B]
    char* Bb = lds + 131072;          // 2 x [1024 units of 16B]

    const int tid = threadIdx.x;
    const int l = tid & 63;
    const int w = tid >> 6;           // wave 0..7
    const int wrow = w >> 2;          // 0..1
    const int wcol = w & 3;           // 0..3
    const int rowBase = blockIdx.x * 128;

    // ---- stage A panel once: 16 rows per wave, 1 DMA (=1 KiB row) each
#pragma unroll
    for (int i = 0; i < 16; ++i) {
        const int r = w * 16 + i;                      // wave-uniform
        gl_lds16(Zh + (size_t)(rowBase + r) * DIM + (l ^ (r & 7)) * 8,
                 Ab + r * 1024 + l * 16);
    }

    // B layout: unit u(c,s) = c*4 + (s ^ ((c>>1)&3)), c=col 0..255, s=kslot 0..3
#define STAGE_B(buf, stp) do {                                                 \
        const int _tile = (stp) >> 4, _ks = (stp) & 15;                        \
        _Pragma("unroll")                                                      \
        for (int _i = 0; _i < 2; ++_i) {                                       \
            const int _u = w * 128 + _i * 64 + l;                              \
            const int _c = _u >> 2;                                            \
            const int _s = (_u & 3) ^ ((_c >> 1) & 3);                         \
            gl_lds16(Eh + (size_t)(_tile * 256 + _c) * DIM + _ks * 32 + _s * 8,\
                     Bb + (buf) * 16384 + w * 2048 + _i * 1024 + l * 16);      \
        }                                                                      \
    } while (0)

    STAGE_B(0, 0);
    STAGE_B(1, 1);

    float runmax[16];
#pragma unroll
    for (int q = 0; q < 16; ++q) runmax[q] = -__builtin_inff();

    for (int tile = 0; tile < 32; ++tile) {
        f32x4 acc[4][4];
#pragma unroll
        for (int m = 0; m < 4; ++m)
#pragma unroll
            for (int n = 0; n < 4; ++n) acc[m][n] = (f32x4){0.f, 0.f, 0.f, 0.f};

        for (int ks = 0; ks < 16; ++ks) {
            const int step = tile * 16 + ks;
            // wait current B buffer (and A on step 0); one batch stays in flight
            if (step == 511) asm volatile("s_waitcnt vmcnt(0)" ::: "memory");
            else             asm volatile("s_waitcnt vmcnt(2)" ::: "memory");
            asm volatile("s_barrier" ::: "memory");

            const char* B0 = Bb + (step & 1) * 16384;
            f16x8 af[4], bf[4];
#pragma unroll
            for (int m = 0; m < 4; ++m) {
                const int rr = wrow * 64 + m * 16 + (l & 15);
                const int sa = ks * 4 + (l >> 4);
                af[m] = *(const f16x8*)(Ab + rr * 1024 + (sa ^ (rr & 7)) * 16);
            }
#pragma unroll
            for (int n = 0; n < 4; ++n) {
                const int c = wcol * 64 + n * 16 + (l & 15);
                const int ub = c * 4 + ((l >> 4) ^ ((c >> 1) & 3));
                bf[n] = *(const f16x8*)(B0 + ub * 16);
            }
            __builtin_amdgcn_s_setprio(1);
#pragma unroll
            for (int m = 0; m < 4; ++m)
#pragma unroll
                for (int n = 0; n < 4; ++n)
                    acc[m][n] = __builtin_amdgcn_mfma_f32_16x16x32_f16(af[m], bf[n], acc[m][n], 0, 0, 0);
            __builtin_amdgcn_s_setprio(0);

            if (ks == 15) {
                // epilogue: screen on raw scaled dot (ee folded into THR)
#pragma unroll
                for (int m = 0; m < 4; ++m) {
#pragma unroll
                    for (int r = 0; r < 4; ++r) {
                        float mx = fmaxf(fmaxf(acc[m][0][r], acc[m][1][r]),
                                         fmaxf(acc[m][2][r], acc[m][3][r]));
#pragma unroll
                        for (int off = 1; off < 16; off <<= 1)
                            mx = fmaxf(mx, __shfl_xor(mx, off, 64));
                        const int q = m * 4 + r;
                        const float rm = fmaxf(runmax[q], mx);
                        runmax[q] = rm;
                        const float thr = rm - THR;
                        const int rowg = rowBase + wrow * 64 + m * 16 + (l >> 4) * 4 + r;
#pragma unroll
                        for (int n = 0; n < 4; ++n) {
                            if (acc[m][n][r] >= thr) {
                                unsigned pos = atomicAdd(&cnt[rowg], 1u);
                                if (pos < CAP)
                                    cand[(size_t)rowg * CAP + pos] =
                                        (unsigned)(tile * 256 + wcol * 64 + n * 16 + (l & 15));
                            }
                        }
                    }
                }
            }

            // my ds_reads landed in regs before anyone overwrites this buffer
            asm volatile("s_waitcnt lgkmcnt(0)" ::: "memory");
            asm volatile("s_barrier" ::: "memory");
            if (step + 2 < 512) STAGE_B(step & 1, step + 2);
        }
    }
#undef STAGE_B
}

// ---------------------------------------------------------------------------
// finish: rescore (exact, bit-identical chain) + gather + loss, fused.
// 1024 blocks x 256 thr (4 waves); each wave handles 8 rows sequentially.
// One f64 loss atomic per block.
// ---------------------------------------------------------------------------
__global__ __launch_bounds__(256)
void finish_kernel(const float* __restrict__ Z, const float* __restrict__ E,
                   const float* __restrict__ zz, const float* __restrict__ ee,
                   const unsigned int* __restrict__ cnt,
                   const unsigned int* __restrict__ cand,
                   float* __restrict__ outZ, float* __restrict__ outIdxF,
                   double* __restrict__ lossAcc) {
    __shared__ double psum[4];
    const int tid = threadIdx.x;
    const int l = tid & 63;
    const int w = tid >> 6;
    double s = 0.0;

    for (int j = 0; j < 8; ++j) {
        const int row = blockIdx.x * 32 + w * 8 + j;
        unsigned c = cnt[row]; if (c > CAP) c = CAP;
        int kk;
        if (c == 1) {
            kk = (int)cand[(size_t)row * CAP];
        } else {
            float d2 = __builtin_inff();
            int kl = 0x7FFFFFFF;
            if (l < (int)c) {
                int k = (int)cand[(size_t)row * CAP + l];
                const float4* zr4 = (const float4*)(Z + (size_t)row * DIM);
                const float4* er4 = (const float4*)(E + (size_t)k * DIM);
                float acc = 0.0f;
#pragma unroll 8
                for (int i = 0; i < DIM / 4; ++i) {
                    float4 z4 = zr4[i], e4 = er4[i];
                    acc = __builtin_fmaf(z4.x, e4.x, acc);
                    acc = __builtin_fmaf(z4.y, e4.y, acc);
                    acc = __builtin_fmaf(z4.z, e4.z, acc);
                    acc = __builtin_fmaf(z4.w, e4.w, acc);
                }
                float t = __builtin_fmaf(-2.0f, acc, zz[row]);
                d2 = __fadd_rn(t, ee[k]);
                kl = k;
            }
#pragma unroll
            for (int off = 32; off > 0; off >>= 1) {
                float od = __shfl_down(d2, off, 64);
                int ok = __shfl_down(kl, off, 64);
                if (od < d2 || (od == d2 && ok < kl)) { d2 = od; kl = ok; }
            }
            kk = __shfl(kl, 0, 64);
        }
        // gather + straight-through + loss partial
        const float* zr = Z + (size_t)row * DIM;
        const float* er = E + (size_t)kk * DIM;
        float* orow = outZ + (size_t)row * DIM;
#pragma unroll
        for (int i = 0; i < 2; ++i) {
            int off = (l + i * 64) * 4;
            float4 z4 = *(const float4*)(zr + off);
            float4 e4 = *(const float4*)(er + off);
            float dx = __fsub_rn(e4.x, z4.x);
            float dy = __fsub_rn(e4.y, z4.y);
            float dz = __fsub_rn(e4.z, z4.z);
            float dw = __fsub_rn(e4.w, z4.w);
            float4 st;
            st.x = __fadd_rn(z4.x, dx);
            st.y = __fadd_rn(z4.y, dy);
            st.z = __fadd_rn(z4.z, dz);
            st.w = __fadd_rn(z4.w, dw);
            *(float4*)(orow + off) = st;
            s += (double)dx * dx + (double)dy * dy + (double)dz * dz + (double)dw * dw;
        }
        if (l == 0) outIdxF[row] = (float)kk;
    }
#pragma unroll
    for (int o = 32; o > 0; o >>= 1) s += __shfl_down(s, o, 64);
    if (l == 0) psum[w] = s;
    __syncthreads();
    if (tid == 0)
        atomicAdd(lossAcc, psum[0] + psum[1] + psum[2] + psum[3]);
}

__global__ void finalize_kernel(const double* __restrict__ lossAcc,
                                float* __restrict__ outLoss) {
    double m = *lossAcc / (double)((size_t)NROWS * DIM);
    float mf = (float)m;
    float c = __fmul_rn(0.25f, mf);
    *outLoss = __fadd_rn(c, mf);
}

// ---------------------------------------------------------------------------
// Fallback (ws too small): round-1 proven-correct VALU path, verbatim.
// ---------------------------------------------------------------------------
__device__ __forceinline__ float pairwise512_sq(const float* __restrict__ p) {
    float blk[4];
#pragma unroll
    for (int b = 0; b < 4; ++b) {
        const float* a = p + b * 128;
        float r[8];
#pragma unroll
        for (int j = 0; j < 8; ++j) r[j] = __fmul_rn(a[j], a[j]);
#pragma unroll
        for (int i = 8; i < 128; i += 8) {
#pragma unroll
            for (int j = 0; j < 8; ++j)
                r[j] = __fadd_rn(r[j], __fmul_rn(a[i + j], a[i + j]));
        }
        blk[b] = __fadd_rn(__fadd_rn(__fadd_rn(r[0], r[1]), __fadd_rn(r[2], r[3])),
                           __fadd_rn(__fadd_rn(r[4], r[5]), __fadd_rn(r[6], r[7])));
    }
    return __fadd_rn(__fadd_rn(blk[0], blk[1]), __fadd_rn(blk[2], blk[3]));
}

__global__ __launch_bounds__(512, 2)
void argmin_fallback(const float* __restrict__ Z, const float* __restrict__ E,
                     const float* __restrict__ ee, int* __restrict__ outIdx) {
    __shared__ __align__(16) char smem[(32 * 132 + 32 * 260) * 4];
    float (*As)[132] = (float (*)[132])smem;
    float (*Bs)[260] = (float (*)[260])(smem + 32 * 132 * 4);
    __shared__ float zzs[128];
    const int tid = threadIdx.x;
    const int tx = tid & 31;
    const int ty = tid >> 5;
    const int rowBase = blockIdx.x * 128;
    if (tid < 128) zzs[tid] = pairwise512_sq(Z + (size_t)(rowBase + tid) * DIM);
    __syncthreads();
    float zz[8];
#pragma unroll
    for (int m = 0; m < 8; ++m) zz[m] = zzs[ty * 8 + m];
    float bestV[8]; int bestI[8];
#pragma unroll
    for (int m = 0; m < 8; ++m) { bestV[m] = __builtin_inff(); bestI[m] = 0; }
    for (int tile = 0; tile < 32; ++tile) {
        float acc[8][8];
#pragma unroll
        for (int m = 0; m < 8; ++m)
#pragma unroll
            for (int n = 0; n < 8; ++n) acc[m][n] = 0.0f;
        for (int kc = 0; kc < DIM; kc += 32) {
            __syncthreads();
#pragma unroll
            for (int i = 0; i < 2; ++i) {
                int id4 = tid + i * 512;
                int r = id4 >> 3, c = id4 & 7;
                float4 v = *(const float4*)(Z + (size_t)(rowBase + r) * DIM + kc + c * 4);
                As[c * 4 + 0][r] = v.x; As[c * 4 + 1][r] = v.y;
                As[c * 4 + 2][r] = v.z; As[c * 4 + 3][r] = v.w;
            }
#pragma unroll
            for (int i = 0; i < 4; ++i) {
                int id4 = tid + i * 512;
                int r = id4 >> 3, c = id4 & 7;
                float4 v = *(const float4*)(E + (size_t)(tile * 256 + r) * DIM + kc + c * 4);
                Bs[c * 4 + 0][r] = v.x; Bs[c * 4 + 1][r] = v.y;
                Bs[c * 4 + 2][r] = v.z; Bs[c * 4 + 3][r] = v.w;
            }
            __syncthreads();
#pragma unroll
            for (int kk = 0; kk < 32; ++kk) {
                float a[8], b[8];
                *(float4*)&a[0] = *(const float4*)&As[kk][ty * 8];
                *(float4*)&a[4] = *(const float4*)&As[kk][ty * 8 + 4];
                *(float4*)&b[0] = *(const float4*)&Bs[kk][tx * 8];
                *(float4*)&b[4] = *(const float4*)&Bs[kk][tx * 8 + 4];
#pragma unroll
                for (int m = 0; m < 8; ++m)
#pragma unroll
                    for (int n = 0; n < 8; ++n)
                        acc[m][n] = __builtin_fmaf(a[m], b[n], acc[m][n]);
            }
        }
#pragma unroll
        for (int m = 0; m < 8; ++m) {
#pragma unroll
            for (int n = 0; n < 8; ++n) {
                float t = __builtin_fmaf(-2.0f, acc[m][n], zz[m]);
                float d2 = __fadd_rn(t, ee[tile * 256 + tx * 8 + n]);
                int kidx = tile * 256 + tx * 8 + n;
                if (d2 < bestV[m]) { bestV[m] = d2; bestI[m] = kidx; }
            }
        }
    }
    __syncthreads();
    float (*redV)[33] = (float (*)[33])smem;
    int   (*redI)[33] = (int (*)[33])(smem + 128 * 33 * 4);
#pragma unroll
    for (int m = 0; m < 8; ++m) {
        redV[ty * 8 + m][tx] = bestV[m];
        redI[ty * 8 + m][tx] = bestI[m];
    }
    __syncthreads();
    if (tid < 128) {
        float bv = redV[tid][0]; int bi = redI[tid][0];
        for (int j = 1; j < 32; ++j) {
            float v = redV[tid][j]; int ii = redI[tid][j];
            if (v < bv || (v == bv && ii < bi)) { bv = v; bi = ii; }
        }
        outIdx[rowBase + tid] = bi;
    }
}

__global__ void gather_kernel(const float* __restrict__ Z, const float* __restrict__ E,
                              const int* __restrict__ idx, float* __restrict__ outZ,
                              float* __restrict__ outIdxF, double* __restrict__ lossAcc) {
    int row = blockIdx.x;
    int t = threadIdx.x;  // 64
    int k = idx[row];
    const float* zr = Z + (size_t)row * DIM;
    const float* er = E + (size_t)k * DIM;
    float* orow = outZ + (size_t)row * DIM;
    double s = 0.0;
#pragma unroll
    for (int i = 0; i < 2; ++i) {
        int off = (t + i * 64) * 4;
        float4 z4 = *(const float4*)(zr + off);
        float4 e4 = *(const float4*)(er + off);
        float dx = __fsub_rn(e4.x, z4.x);
        float dy = __fsub_rn(e4.y, z4.y);
        float dz = __fsub_rn(e4.z, z4.z);
        float dw = __fsub_rn(e4.w, z4.w);
        float4 st;
        st.x = __fadd_rn(z4.x, dx);
        st.y = __fadd_rn(z4.y, dy);
        st.z = __fadd_rn(z4.z, dz);
        st.w = __fadd_rn(z4.w, dw);
        *(float4*)(orow + off) = st;
        s += (double)dx * dx + (double)dy * dy + (double)dz * dz + (double)dw * dw;
    }
#pragma unroll
    for (int o = 32; o > 0; o >>= 1) s += __shfl_down(s, o, 64);
    if (t == 0) {
        atomicAdd(lossAcc, s);
        outIdxF[row] = (float)k;
    }
}

// ---------------------------------------------------------------------------
extern "C" void kernel_launch(void* const* d_in, const int* in_sizes, int n_in,
                              void* d_out, int out_size, void* d_ws, size_t ws_size,
                              hipStream_t stream) {
    const float* Z = (const float*)d_in[0];
    const float* E = (const float*)d_in[1];
    float* out = (float*)d_out;
    float* zq_out = out;
    float* loss_out = out + (size_t)NROWS * DIM;
    float* idxf_out = loss_out + 1;

    if (ws_size >= WS_NEEDED) {
        _Float16* Zh = (_Float16*)((char*)d_ws + OFF_ZH);
        _Float16* Eh = (_Float16*)((char*)d_ws + OFF_EH);
        float* ee = (float*)((char*)d_ws + OFF_EE);
        float* zz = (float*)((char*)d_ws + OFF_ZZ);
        unsigned int* cnt = (unsigned int*)((char*)d_ws + OFF_CNT);
        unsigned int* cand = (unsigned int*)((char*)d_ws + OFF_CAND);
        double* lossAcc = (double*)((char*)d_ws + OFF_LOSS);

        hipMemsetAsync(cnt, 0, NROWS * sizeof(unsigned int), stream);
        hipMemsetAsync(lossAcc, 0, sizeof(double), stream);
        cvt_kernel<<<(NROWS * DIM / 8 + 255) / 256, 256, 0, stream>>>(Z, Zh, NROWS * DIM / 8, 1.0f);
        cvt_kernel<<<(KCB * DIM / 8 + 255) / 256, 256, 0, stream>>>(E, Eh, KCB * DIM / 8, 8192.0f);
        ee_kernel<<<KCB / 256, 256, 0, stream>>>(E, ee);
        zz_kernel<<<NROWS / 256, 256, 0, stream>>>(Z, zz);
        screen_kernel<<<NROWS / 128, 512, 0, stream>>>(Zh, Eh, cnt, cand);
        finish_kernel<<<NROWS / 32, 256, 0, stream>>>(Z, E, zz, ee, cnt, cand,
                                                      zq_out, idxf_out, lossAcc);
        finalize_kernel<<<1, 1, 0, stream>>>(lossAcc, loss_out);
    } else {
        float* ee = (float*)d_ws;
        int* idx = (int*)((char*)d_ws + 32768);
        double* lossAcc = (double*)((char*)d_ws + 163840);
        hipMemsetAsync(lossAcc, 0, sizeof(double), stream);
        ee_kernel<<<KCB / 256, 256, 0, stream>>>(E, ee);
        argmin_fallback<<<NROWS / 128, 512, 0, stream>>>(Z, E, ee, idx);
        gather_kernel<<<NROWS, 64, 0, stream>>>(Z, E, idx, zq_out, idxf_out, lossAcc);
        finalize_kernel<<<1, 1, 0, stream>>>(lossAcc, loss_out);
    }
}

// Round 6
// 982.876 us; speedup vs baseline: 1.6548x; 1.0264x over previous
//
#include <hip/hip_runtime.h>
#include <math.h>

#define DIM    512
#define KCB    8192
#define NROWS  32768

typedef _Float16 f16x8 __attribute__((ext_vector_type(8)));
typedef float    f32x4 __attribute__((ext_vector_type(4)));

// ---- workspace layout (main path) ----
#define OFF_ZH    0ull                    // f16 Z  [32768][512] = 33554432 B
#define OFF_EH    33554432ull             // f16 E*8192 [8192][512] = 8388608 B
#define OFF_EE    41943040ull             // f32 ee [8192]
#define OFF_ZZ    41975808ull             // f32 zz [32768]
#define OFF_CNT   42106880ull             // u32 cnt[32768]            (memset w/ loss)
#define OFF_LOSS  42237952ull             // f64 loss accumulator
#define OFF_CAND  42237960ull             // u32 cand[32768][64]
#define WS_NEEDED 50626568ull
#define CAP 64
// screen keeps k if dot16_scaled >= runmax - THR. Scale = 2^13 on E.
// Equivalent dot-margin 2.5e-4 (r3-proven); required slack ~1.2e-4.
#define THR 2.048f

// direct-to-LDS 16B DMA (dest = wave-uniform base + lane*16; swizzle goes on
// the per-lane GLOBAL source address)
__device__ __forceinline__ void gl_lds16(const void* g, void* l) {
    __builtin_amdgcn_global_load_lds(
        (const __attribute__((address_space(1))) unsigned int*)g,
        (__attribute__((address_space(3))) unsigned int*)l, 16, 0, 0);
}

// ---------------------------------------------------------------------------
// numpy-pairwise sum of squares, 512 floats (numerics-critical, unchanged).
// ---------------------------------------------------------------------------
__device__ __forceinline__ float pairwise512_sq_v(const float* __restrict__ p) {
    float blk[4];
#pragma unroll
    for (int b = 0; b < 4; ++b) {
        const float4* a4 = (const float4*)(p + b * 128);
        float4 v0 = a4[0], v1 = a4[1];
        float r[8];
        r[0] = __fmul_rn(v0.x, v0.x); r[1] = __fmul_rn(v0.y, v0.y);
        r[2] = __fmul_rn(v0.z, v0.z); r[3] = __fmul_rn(v0.w, v0.w);
        r[4] = __fmul_rn(v1.x, v1.x); r[5] = __fmul_rn(v1.y, v1.y);
        r[6] = __fmul_rn(v1.z, v1.z); r[7] = __fmul_rn(v1.w, v1.w);
#pragma unroll
        for (int i = 1; i < 16; ++i) {
            v0 = a4[i * 2]; v1 = a4[i * 2 + 1];
            r[0] = __fadd_rn(r[0], __fmul_rn(v0.x, v0.x));
            r[1] = __fadd_rn(r[1], __fmul_rn(v0.y, v0.y));
            r[2] = __fadd_rn(r[2], __fmul_rn(v0.z, v0.z));
            r[3] = __fadd_rn(r[3], __fmul_rn(v0.w, v0.w));
            r[4] = __fadd_rn(r[4], __fmul_rn(v1.x, v1.x));
            r[5] = __fadd_rn(r[5], __fmul_rn(v1.y, v1.y));
            r[6] = __fadd_rn(r[6], __fmul_rn(v1.z, v1.z));
            r[7] = __fadd_rn(r[7], __fmul_rn(v1.w, v1.w));
        }
        blk[b] = __fadd_rn(__fadd_rn(__fadd_rn(r[0], r[1]), __fadd_rn(r[2], r[3])),
                           __fadd_rn(__fadd_rn(r[4], r[5]), __fadd_rn(r[6], r[7])));
    }
    return __fadd_rn(__fadd_rn(blk[0], blk[1]), __fadd_rn(blk[2], blk[3]));
}

__global__ void ee_kernel(const float* __restrict__ E, float* __restrict__ ee) {
    int k = blockIdx.x * blockDim.x + threadIdx.x;
    if (k < KCB) ee[k] = pairwise512_sq_v(E + (size_t)k * DIM);
}

__global__ void zz_kernel(const float* __restrict__ Z, float* __restrict__ zz) {
    int r = blockIdx.x * blockDim.x + threadIdx.x;
    if (r < NROWS) zz[r] = pairwise512_sq_v(Z + (size_t)r * DIM);
}

// f32 -> f16 (RNE) with optional exact power-of-2 prescale
__global__ void cvt_kernel(const float* __restrict__ in, _Float16* __restrict__ out,
                           int n8, float scale) {
    int i = blockIdx.x * blockDim.x + threadIdx.x;
    if (i >= n8) return;
    const float4* p = (const float4*)in + (size_t)i * 2;
    float4 v0 = p[0], v1 = p[1];
    f16x8 h;
    h[0] = (_Float16)(v0.x * scale); h[1] = (_Float16)(v0.y * scale);
    h[2] = (_Float16)(v0.z * scale); h[3] = (_Float16)(v0.w * scale);
    h[4] = (_Float16)(v1.x * scale); h[5] = (_Float16)(v1.y * scale);
    h[6] = (_Float16)(v1.z * scale); h[7] = (_Float16)(v1.w * scale);
    *(f16x8*)(out + (size_t)i * 8) = h;
}

// ---------------------------------------------------------------------------
// Screen v4: 256 blocks x 512 thr (8 waves, 2 wrow x 4 wcol). Block = 128
// rows x all 8192 cols (32 tiles of 256) x K=512 (16 ksteps of 32). Both
// A[128x32] (8 KiB) and B[256x32] (16 KiB) f16 tiles are ring-3 staged via
// global_load_lds (LDS 72 KiB). One barrier per step:
//   vmcnt(3)   -> own batch-s DMAs retired
//   s_barrier  -> ALL waves' batch-s retired => buffer s complete in LDS
//   STAGE(s+2) -> overwrites slot (s-1)%3, whose reads were consumed before
//                 this barrier (MFMA issue implies lgkm waits passed)
//   frag reads + setprio-wrapped 16 MFMA
// Waves may slip within a step => ds_read/MFMA overlap across waves.
// Unit layout (both tiles): u = row*4 + (kslot ^ ((row>>1)&3)) -> enumerated
// bank-conflict-free for the 16-lane frag-read groups.
// Epilogue per tile: dot-max screen (ee folded into THR), rare atomics.
// ---------------------------------------------------------------------------
__global__ __launch_bounds__(512, 2)
void screen_kernel(const _Float16* __restrict__ Zh, const _Float16* __restrict__ Eh,
                   unsigned int* __restrict__ cnt, unsigned int* __restrict__ cand) {
    __shared__ __align__(16) char lds[3 * 8192 + 3 * 16384];  // 72 KiB
    char* Ab = lds;               // 3 x [128r x 4u] x 16B
    char* Bb = lds + 3 * 8192;    // 3 x [256c x 4u] x 16B

    const int tid = threadIdx.x;
    const int l = tid & 63;
    const int w = tid >> 6;           // wave 0..7
    const int wrow = w >> 2;          // 0..1
    const int wcol = w & 3;           // 0..3
    const int rowBase = blockIdx.x * 128;

    // stage batch for step `stp` into ring slot `slot`:
    // A: 512 units, 64/wave (1 DMA); B: 1024 units, 128/wave (2 DMAs)
#define STAGE(stp, slot) do {                                                  \
        const int _tile = (stp) >> 4, _ks = (stp) & 15;                        \
        { const int _u = w * 64 + l;                                           \
          const int _r = _u >> 2;                                              \
          const int _s = (_u & 3) ^ ((_r >> 1) & 3);                           \
          gl_lds16(Zh + (size_t)(rowBase + _r) * DIM + _ks * 32 + _s * 8,      \
                   Ab + (slot) * 8192 + w * 1024 + l * 16); }                  \
        _Pragma("unroll")                                                      \
        for (int _i = 0; _i < 2; ++_i) {                                       \
          const int _u = w * 128 + _i * 64 + l;                                \
          const int _c = _u >> 2;                                              \
          const int _s = (_u & 3) ^ ((_c >> 1) & 3);                           \
          gl_lds16(Eh + (size_t)(_tile * 256 + _c) * DIM + _ks * 32 + _s * 8,  \
                   Bb + (slot) * 16384 + w * 2048 + _i * 1024 + l * 16); }     \
    } while (0)

    STAGE(0, 0);
    STAGE(1, 1);

    // per-slot frag byte offsets are step-invariant: precompute
    int offA[4], offB[4];
#pragma unroll
    for (int m = 0; m < 4; ++m) {
        const int rr = wrow * 64 + m * 16 + (l & 15);
        offA[m] = (rr * 4 + ((l >> 4) ^ ((rr >> 1) & 3))) * 16;
    }
#pragma unroll
    for (int n = 0; n < 4; ++n) {
        const int c = wcol * 64 + n * 16 + (l & 15);
        offB[n] = (c * 4 + ((l >> 4) ^ ((c >> 1) & 3))) * 16;
    }

    float runmax[16];
#pragma unroll
    for (int q = 0; q < 16; ++q) runmax[q] = -__builtin_inff();

    int rs = 0;      // read slot  = step % 3
    int ss = 2;      // stage slot = (step+2) % 3

    for (int tile = 0; tile < 32; ++tile) {
        f32x4 acc[4][4];
#pragma unroll
        for (int m = 0; m < 4; ++m)
#pragma unroll
            for (int n = 0; n < 4; ++n) acc[m][n] = (f32x4){0.f, 0.f, 0.f, 0.f};

        for (int ks = 0; ks < 16; ++ks) {
            const int step = tile * 16 + ks;
            // own batch-s retired (batch s+1 = newest 3 may remain)
            if (step < 511) asm volatile("s_waitcnt vmcnt(3)" ::: "memory");
            else            asm volatile("s_waitcnt vmcnt(0)" ::: "memory");
            // all waves' batch-s retired => buffer rs complete
            asm volatile("s_barrier" ::: "memory");
            if (step + 2 < 512) STAGE(step + 2, ss);

            const char* A0 = Ab + rs * 8192;
            const char* B0 = Bb + rs * 16384;
            f16x8 af[4], bf[4];
#pragma unroll
            for (int m = 0; m < 4; ++m) af[m] = *(const f16x8*)(A0 + offA[m]);
#pragma unroll
            for (int n = 0; n < 4; ++n) bf[n] = *(const f16x8*)(B0 + offB[n]);

            __builtin_amdgcn_s_setprio(1);
#pragma unroll
            for (int m = 0; m < 4; ++m)
#pragma unroll
                for (int n = 0; n < 4; ++n)
                    acc[m][n] = __builtin_amdgcn_mfma_f32_16x16x32_f16(af[m], bf[n], acc[m][n], 0, 0, 0);
            __builtin_amdgcn_s_setprio(0);

            rs = (rs == 2) ? 0 : rs + 1;
            ss = (ss == 2) ? 0 : ss + 1;
        }

        // epilogue: screen on raw scaled dot (ee folded into THR)
#pragma unroll
        for (int m = 0; m < 4; ++m) {
#pragma unroll
            for (int r = 0; r < 4; ++r) {
                float mx = fmaxf(fmaxf(acc[m][0][r], acc[m][1][r]),
                                 fmaxf(acc[m][2][r], acc[m][3][r]));
#pragma unroll
                for (int off = 1; off < 16; off <<= 1)
                    mx = fmaxf(mx, __shfl_xor(mx, off, 64));
                const int q = m * 4 + r;
                const float rm = fmaxf(runmax[q], mx);
                runmax[q] = rm;
                const float thr = rm - THR;
                const int rowg = rowBase + wrow * 64 + m * 16 + (l >> 4) * 4 + r;
#pragma unroll
                for (int n = 0; n < 4; ++n) {
                    if (acc[m][n][r] >= thr) {
                        unsigned pos = atomicAdd(&cnt[rowg], 1u);
                        if (pos < CAP)
                            cand[(size_t)rowg * CAP + pos] =
                                (unsigned)(tile * 256 + wcol * 64 + n * 16 + (l & 15));
                    }
                }
            }
        }
    }
#undef STAGE
}

// ---------------------------------------------------------------------------
// finish: rescore (exact, bit-identical chain) + gather + loss, fused.
// ---------------------------------------------------------------------------
__global__ __launch_bounds__(256)
void finish_kernel(const float* __restrict__ Z, const float* __restrict__ E,
                   const float* __restrict__ zz, const float* __restrict__ ee,
                   const unsigned int* __restrict__ cnt,
                   const unsigned int* __restrict__ cand,
                   float* __restrict__ outZ, float* __restrict__ outIdxF,
                   double* __restrict__ lossAcc) {
    __shared__ double psum[4];
    const int tid = threadIdx.x;
    const int l = tid & 63;
    const int w = tid >> 6;
    double s = 0.0;

    for (int j = 0; j < 8; ++j) {
        const int row = blockIdx.x * 32 + w * 8 + j;
        unsigned c = cnt[row]; if (c > CAP) c = CAP;
        int kk;
        if (c == 1) {
            kk = (int)cand[(size_t)row * CAP];
        } else {
            float d2 = __builtin_inff();
            int kl = 0x7FFFFFFF;
            if (l < (int)c) {
                int k = (int)cand[(size_t)row * CAP + l];
                const float4* zr4 = (const float4*)(Z + (size_t)row * DIM);
                const float4* er4 = (const float4*)(E + (size_t)k * DIM);
                float acc = 0.0f;
#pragma unroll 8
                for (int i = 0; i < DIM / 4; ++i) {
                    float4 z4 = zr4[i], e4 = er4[i];
                    acc = __builtin_fmaf(z4.x, e4.x, acc);
                    acc = __builtin_fmaf(z4.y, e4.y, acc);
                    acc = __builtin_fmaf(z4.z, e4.z, acc);
                    acc = __builtin_fmaf(z4.w, e4.w, acc);
                }
                float t = __builtin_fmaf(-2.0f, acc, zz[row]);
                d2 = __fadd_rn(t, ee[k]);
                kl = k;
            }
#pragma unroll
            for (int off = 32; off > 0; off >>= 1) {
                float od = __shfl_down(d2, off, 64);
                int ok = __shfl_down(kl, off, 64);
                if (od < d2 || (od == d2 && ok < kl)) { d2 = od; kl = ok; }
            }
            kk = __shfl(kl, 0, 64);
        }
        const float* zr = Z + (size_t)row * DIM;
        const float* er = E + (size_t)kk * DIM;
        float* orow = outZ + (size_t)row * DIM;
#pragma unroll
        for (int i = 0; i < 2; ++i) {
            int off = (l + i * 64) * 4;
            float4 z4 = *(const float4*)(zr + off);
            float4 e4 = *(const float4*)(er + off);
            float dx = __fsub_rn(e4.x, z4.x);
            float dy = __fsub_rn(e4.y, z4.y);
            float dz = __fsub_rn(e4.z, z4.z);
            float dw = __fsub_rn(e4.w, z4.w);
            float4 st;
            st.x = __fadd_rn(z4.x, dx);
            st.y = __fadd_rn(z4.y, dy);
            st.z = __fadd_rn(z4.z, dz);
            st.w = __fadd_rn(z4.w, dw);
            *(float4*)(orow + off) = st;
            s += (double)dx * dx + (double)dy * dy + (double)dz * dz + (double)dw * dw;
        }
        if (l == 0) outIdxF[row] = (float)kk;
    }
#pragma unroll
    for (int o = 32; o > 0; o >>= 1) s += __shfl_down(s, o, 64);
    if (l == 0) psum[w] = s;
    __syncthreads();
    if (tid == 0)
        atomicAdd(lossAcc, psum[0] + psum[1] + psum[2] + psum[3]);
}

__global__ void finalize_kernel(const double* __restrict__ lossAcc,
                                float* __restrict__ outLoss) {
    double m = *lossAcc / (double)((size_t)NROWS * DIM);
    float mf = (float)m;
    float c = __fmul_rn(0.25f, mf);
    *outLoss = __fadd_rn(c, mf);
}

// ---------------------------------------------------------------------------
// Fallback (ws too small): round-1 proven-correct VALU path, verbatim.
// ---------------------------------------------------------------------------
__device__ __forceinline__ float pairwise512_sq(const float* __restrict__ p) {
    float blk[4];
#pragma unroll
    for (int b = 0; b < 4; ++b) {
        const float* a = p + b * 128;
        float r[8];
#pragma unroll
        for (int j = 0; j < 8; ++j) r[j] = __fmul_rn(a[j], a[j]);
#pragma unroll
        for (int i = 8; i < 128; i += 8) {
#pragma unroll
            for (int j = 0; j < 8; ++j)
                r[j] = __fadd_rn(r[j], __fmul_rn(a[i + j], a[i + j]));
        }
        blk[b] = __fadd_rn(__fadd_rn(__fadd_rn(r[0], r[1]), __fadd_rn(r[2], r[3])),
                           __fadd_rn(__fadd_rn(r[4], r[5]), __fadd_rn(r[6], r[7])));
    }
    return __fadd_rn(__fadd_rn(blk[0], blk[1]), __fadd_rn(blk[2], blk[3]));
}

__global__ __launch_bounds__(512, 2)
void argmin_fallback(const float* __restrict__ Z, const float* __restrict__ E,
                     const float* __restrict__ ee, int* __restrict__ outIdx) {
    __shared__ __align__(16) char smem[(32 * 132 + 32 * 260) * 4];
    float (*As)[132] = (float (*)[132])smem;
    float (*Bs)[260] = (float (*)[260])(smem + 32 * 132 * 4);
    __shared__ float zzs[128];
    const int tid = threadIdx.x;
    const int tx = tid & 31;
    const int ty = tid >> 5;
    const int rowBase = blockIdx.x * 128;
    if (tid < 128) zzs[tid] = pairwise512_sq(Z + (size_t)(rowBase + tid) * DIM);
    __syncthreads();
    float zz[8];
#pragma unroll
    for (int m = 0; m < 8; ++m) zz[m] = zzs[ty * 8 + m];
    float bestV[8]; int bestI[8];
#pragma unroll
    for (int m = 0; m < 8; ++m) { bestV[m] = __builtin_inff(); bestI[m] = 0; }
    for (int tile = 0; tile < 32; ++tile) {
        float acc[8][8];
#pragma unroll
        for (int m = 0; m < 8; ++m)
#pragma unroll
            for (int n = 0; n < 8; ++n) acc[m][n] = 0.0f;
        for (int kc = 0; kc < DIM; kc += 32) {
            __syncthreads();
#pragma unroll
            for (int i = 0; i < 2; ++i) {
                int id4 = tid + i * 512;
                int r = id4 >> 3, c = id4 & 7;
                float4 v = *(const float4*)(Z + (size_t)(rowBase + r) * DIM + kc + c * 4);
                As[c * 4 + 0][r] = v.x; As[c * 4 + 1][r] = v.y;
                As[c * 4 + 2][r] = v.z; As[c * 4 + 3][r] = v.w;
            }
#pragma unroll
            for (int i = 0; i < 4; ++i) {
                int id4 = tid + i * 512;
                int r = id4 >> 3, c = id4 & 7;
                float4 v = *(const float4*)(E + (size_t)(tile * 256 + r) * DIM + kc + c * 4);
                Bs[c * 4 + 0][r] = v.x; Bs[c * 4 + 1][r] = v.y;
                Bs[c * 4 + 2][r] = v.z; Bs[c * 4 + 3][r] = v.w;
            }
            __syncthreads();
#pragma unroll
            for (int kk = 0; kk < 32; ++kk) {
                float a[8], b[8];
                *(float4*)&a[0] = *(const float4*)&As[kk][ty * 8];
                *(float4*)&a[4] = *(const float4*)&As[kk][ty * 8 + 4];
                *(float4*)&b[0] = *(const float4*)&Bs[kk][tx * 8];
                *(float4*)&b[4] = *(const float4*)&Bs[kk][tx * 8 + 4];
#pragma unroll
                for (int m = 0; m < 8; ++m)
#pragma unroll
                    for (int n = 0; n < 8; ++n)
                        acc[m][n] = __builtin_fmaf(a[m], b[n], acc[m][n]);
            }
        }
#pragma unroll
        for (int m = 0; m < 8; ++m) {
#pragma unroll
            for (int n = 0; n < 8; ++n) {
                float t = __builtin_fmaf(-2.0f, acc[m][n], zz[m]);
                float d2 = __fadd_rn(t, ee[tile * 256 + tx * 8 + n]);
                int kidx = tile * 256 + tx * 8 + n;
                if (d2 < bestV[m]) { bestV[m] = d2; bestI[m] = kidx; }
            }
        }
    }
    __syncthreads();
    float (*redV)[33] = (float (*)[33])smem;
    int   (*redI)[33] = (int (*)[33])(smem + 128 * 33 * 4);
#pragma unroll
    for (int m = 0; m < 8; ++m) {
        redV[ty * 8 + m][tx] = bestV[m];
        redI[ty * 8 + m][tx] = bestI[m];
    }
    __syncthreads();
    if (tid < 128) {
        float bv = redV[tid][0]; int bi = redI[tid][0];
        for (int j = 1; j < 32; ++j) {
            float v = redV[tid][j]; int ii = redI[tid][j];
            if (v < bv || (v == bv && ii < bi)) { bv = v; bi = ii; }
        }
        outIdx[rowBase + tid] = bi;
    }
}

__global__ void gather_kernel(const float* __restrict__ Z, const float* __restrict__ E,
                              const int* __restrict__ idx, float* __restrict__ outZ,
                              float* __restrict__ outIdxF, double* __restrict__ lossAcc) {
    int row = blockIdx.x;
    int t = threadIdx.x;  // 64
    int k = idx[row];
    const float* zr = Z + (size_t)row * DIM;
    const float* er = E + (size_t)k * DIM;
    float* orow = outZ + (size_t)row * DIM;
    double s = 0.0;
#pragma unroll
    for (int i = 0; i < 2; ++i) {
        int off = (t + i * 64) * 4;
        float4 z4 = *(const float4*)(zr + off);
        float4 e4 = *(const float4*)(er + off);
        float dx = __fsub_rn(e4.x, z4.x);
        float dy = __fsub_rn(e4.y, z4.y);
        float dz = __fsub_rn(e4.z, z4.z);
        float dw = __fsub_rn(e4.w, z4.w);
        float4 st;
        st.x = __fadd_rn(z4.x, dx);
        st.y = __fadd_rn(z4.y, dy);
        st.z = __fadd_rn(z4.z, dz);
        st.w = __fadd_rn(z4.w, dw);
        *(float4*)(orow + off) = st;
        s += (double)dx * dx + (double)dy * dy + (double)dz * dz + (double)dw * dw;
    }
#pragma unroll
    for (int o = 32; o > 0; o >>= 1) s += __shfl_down(s, o, 64);
    if (t == 0) {
        atomicAdd(lossAcc, s);
        outIdxF[row] = (float)k;
    }
}

// ---------------------------------------------------------------------------
extern "C" void kernel_launch(void* const* d_in, const int* in_sizes, int n_in,
                              void* d_out, int out_size, void* d_ws, size_t ws_size,
                              hipStream_t stream) {
    const float* Z = (const float*)d_in[0];
    const float* E = (const float*)d_in[1];
    float* out = (float*)d_out;
    float* zq_out = out;
    float* loss_out = out + (size_t)NROWS * DIM;
    float* idxf_out = loss_out + 1;

    if (ws_size >= WS_NEEDED) {
        _Float16* Zh = (_Float16*)((char*)d_ws + OFF_ZH);
        _Float16* Eh = (_Float16*)((char*)d_ws + OFF_EH);
        float* ee = (float*)((char*)d_ws + OFF_EE);
        float* zz = (float*)((char*)d_ws + OFF_ZZ);
        unsigned int* cnt = (unsigned int*)((char*)d_ws + OFF_CNT);
        unsigned int* cand = (unsigned int*)((char*)d_ws + OFF_CAND);
        double* lossAcc = (double*)((char*)d_ws + OFF_LOSS);

        // cnt[32768] + lossAcc are contiguous: one memset
        hipMemsetAsync(cnt, 0, NROWS * sizeof(unsigned int) + sizeof(double), stream);
        cvt_kernel<<<(NROWS * DIM / 8 + 255) / 256, 256, 0, stream>>>(Z, Zh, NROWS * DIM / 8, 1.0f);
        cvt_kernel<<<(KCB * DIM / 8 + 255) / 256, 256, 0, stream>>>(E, Eh, KCB * DIM / 8, 8192.0f);
        ee_kernel<<<KCB / 256, 256, 0, stream>>>(E, ee);
        zz_kernel<<<NROWS / 256, 256, 0, stream>>>(Z, zz);
        screen_kernel<<<NROWS / 128, 512, 0, stream>>>(Zh, Eh, cnt, cand);
        finish_kernel<<<NROWS / 32, 256, 0, stream>>>(Z, E, zz, ee, cnt, cand,
                                                      zq_out, idxf_out, lossAcc);
        finalize_kernel<<<1, 1, 0, stream>>>(lossAcc, loss_out);
    } else {
        float* ee = (float*)d_ws;
        int* idx = (int*)((char*)d_ws + 32768);
        double* lossAcc = (double*)((char*)d_ws + 163840);
        hipMemsetAsync(lossAcc, 0, sizeof(double), stream);
        ee_kernel<<<KCB / 256, 256, 0, stream>>>(E, ee);
        argmin_fallback<<<NROWS / 128, 512, 0, stream>>>(Z, E, ee, idx);
        gather_kernel<<<NROWS, 64, 0, stream>>>(Z, E, idx, zq_out, idxf_out, lossAcc);
        finalize_kernel<<<1, 1, 0, stream>>>(lossAcc, loss_out);
    }
}